// Round 14
// baseline (152.985 us; speedup 1.0000x reference)
//
#include <hip/hip_runtime.h>
#include <hip/hip_bf16.h>
#include <stdint.h>

// ContrastiveLoss: N=8192, D=512 fp32 features, int labels {0,1}.
// out = mean_i [ (np_i * log(sum_exp_i) - sum_pos_i) / (np_i + 1e-8) ]
// R5: fp8-e4m3 (x16 pre-scale; k pre-permuted identically for A/B).
// R7: XCD swizzle. R9: pipelined LDS dbuf -> sim stuck 46-51 us across 7
//     variants, no pipe >35% -> barrier-latency floor (m97-plateau class).
// R13: PE/PP [row][slot] transpose; fast 128-block final. 117.8 us.
// R14: REGISTER-DIRECT GEMM: 1 wave = one 64x64 tile (8256 single-wave
//     blocks), frags loaded straight from global (16 rows x 64B lines =
//     coalescing-equivalent to staged), NO LDS, NO barriers. Compiler
//     pipelines loads across fully-unrolled K (acc 64 + frags 32 +
//     prefetch 32 = 128 VGPR exactly). L2 read volume 2x (~530 MB) ->
//     ~16 us L2 floor, vs 46 us barrier floor it replaces.
//     Slots (64-tiles): rows->slot bj, cols->slot bi, diag rows-only;
//     row r covered exactly once per slot (cols 0..br-1, diag br,
//     rows br+1..127).

#define N_ROWS 8192
#define DIMF 512
#define DIMB 512
#define NBT 128     // 8192/64 tiles per dim
#define NTRI 8256   // NBT*(NBT+1)/2
#define NSLOT 128
#define SIM_SCALE 0.0390625f  // 10 / 256  (features pre-scaled by 16)

typedef float f32x4 __attribute__((ext_vector_type(4)));
typedef int64_t i64x2 __attribute__((ext_vector_type(2)));

// 4 waves/block, one row per wave: fp32 sumsq -> scale by 16/norm -> fp8,
// k-permuted per 64B tile: orig (c,q) byte-group -> q*16 + c*8 (dot-invariant
// since A and B sides use the same permutation). Block 0 zeroes out[0].
__global__ __launch_bounds__(256) void norm_kernel(const float* __restrict__ x,
                                                   uint8_t* __restrict__ f8,
                                                   float* __restrict__ out) {
    const int wave = threadIdx.x >> 6, t = threadIdx.x & 63;
    const int row = blockIdx.x * 4 + wave;
    const float4* xr = (const float4*)(x + (size_t)row * DIMF);
    float4 v0 = xr[2 * t];
    float4 v1 = xr[2 * t + 1];
    float ss = v0.x * v0.x + v0.y * v0.y + v0.z * v0.z + v0.w * v0.w +
               v1.x * v1.x + v1.y * v1.y + v1.z * v1.z + v1.w * v1.w;
#pragma unroll
    for (int off = 32; off >= 1; off >>= 1) ss += __shfl_xor(ss, off, 64);
    float s = 16.0f / fmaxf(sqrtf(ss), 1e-12f);
    int lo = 0, hi = 0;
    lo = __builtin_amdgcn_cvt_pk_fp8_f32(v0.x * s, v0.y * s, lo, false);
    lo = __builtin_amdgcn_cvt_pk_fp8_f32(v0.z * s, v0.w * s, lo, true);
    hi = __builtin_amdgcn_cvt_pk_fp8_f32(v1.x * s, v1.y * s, hi, false);
    hi = __builtin_amdgcn_cvt_pk_fp8_f32(v1.z * s, v1.w * s, hi, true);
    int2 pk;
    pk.x = lo;
    pk.y = hi;
    const int pos = (t >> 3) * 64 + (t & 3) * 16 + ((t >> 2) & 1) * 8;
    *(int2*)(f8 + (size_t)row * DIMB + pos) = pk;
    if (blockIdx.x == 0 && threadIdx.x == 0) out[0] = 0.0f;
}

// One wave per 64x64 upper-triangle tile. 4x4 MFMA 16x16x32 fp8, frags
// direct from global (b128 = 2 k-steps via the norm-side k-permute).
__global__ __launch_bounds__(64, 4) void sim_kernel(const uint8_t* __restrict__ f8,
                                                    const int* __restrict__ lab,
                                                    float* __restrict__ PE,
                                                    float* __restrict__ PP) {
    // XCD-locality swizzle (8256 = 8 * 1032); upper-tri decode S(b)=b(257-b)/2.
    const int tblk = ((int)blockIdx.x & 7) * 1032 + ((int)blockIdx.x >> 3);
    int bi = (int)(128.5f - sqrtf(128.5f * 128.5f - 2.0f * (float)tblk));
    while (bi * (257 - bi) / 2 > tblk) --bi;
    while ((bi + 1) * (256 - bi) / 2 <= tblk) ++bi;
    const int bj = bi + (tblk - bi * (257 - bi) / 2);
    const bool diag = (bi == bj);

    const int lane = threadIdx.x;
    const int lrow = lane & 15, quad = lane >> 4;
    const int iBase = bi * 64, jBase = bj * 64;

    const uint8_t* pa = f8 + (size_t)(iBase + lrow) * DIMB + quad * 16;
    const uint8_t* pb = f8 + (size_t)(jBase + lrow) * DIMB + quad * 16;

    f32x4 acc[4][4] = {};

#pragma unroll
    for (int kk = 0; kk < 8; ++kk) {
        i64x2 af[4], bfr[4];
#pragma unroll
        for (int m = 0; m < 4; ++m)
            af[m] = *(const i64x2*)(pa + (size_t)(m * 16) * DIMB + kk * 64);
#pragma unroll
        for (int n = 0; n < 4; ++n)
            bfr[n] = *(const i64x2*)(pb + (size_t)(n * 16) * DIMB + kk * 64);
#pragma unroll
        for (int m = 0; m < 4; ++m)
#pragma unroll
            for (int n = 0; n < 4; ++n) {
                acc[m][n] = __builtin_amdgcn_mfma_f32_16x16x32_fp8_fp8(
                    af[m].x, bfr[n].x, acc[m][n], 0, 0, 0);
                acc[m][n] = __builtin_amdgcn_mfma_f32_16x16x32_fp8_fp8(
                    af[m].y, bfr[n].y, acc[m][n], 0, 0, 0);
            }
    }

    // Epilogue. C/D layout: col = lane&15, row = quad*4 + reg (m89-verified).
    int labj[4];
#pragma unroll
    for (int n = 0; n < 4; ++n) labj[n] = lab[jBase + n * 16 + lrow];

    float sec[4] = {0, 0, 0, 0}, spc[4] = {0, 0, 0, 0};

#pragma unroll
    for (int m = 0; m < 4; ++m) {
        float rE[4], rP[4];
#pragma unroll
        for (int e = 0; e < 4; ++e) {
            const int r = m * 16 + quad * 4 + e;
            const int i = iBase + r;
            const int labi = lab[i];
            float se = 0.0f, sp = 0.0f;
            if (diag) {
#pragma unroll
                for (int n = 0; n < 4; ++n) {
                    const int j = jBase + n * 16 + lrow;
                    const float sim = acc[m][n][e] * SIM_SCALE;
                    if (j != i) {
                        se += __expf(sim);
                        if (labj[n] == labi) sp += sim;
                    }
                }
            } else {
#pragma unroll
                for (int n = 0; n < 4; ++n) {
                    const float sim = acc[m][n][e] * SIM_SCALE;
                    const float ex = __expf(sim);
                    se += ex;
                    sec[n] += ex;
                    if (labj[n] == labi) {
                        sp += sim;
                        spc[n] += sim;
                    }
                }
            }
#pragma unroll
            for (int off = 8; off >= 1; off >>= 1) {
                se += __shfl_xor(se, off, 16);
                sp += __shfl_xor(sp, off, 16);
            }
            rE[e] = se;
            rP[e] = sp;
        }
        if (lrow == 0) {
            const int rb = iBase + m * 16 + quad * 4;
#pragma unroll
            for (int e = 0; e < 4; ++e) {
                PE[(size_t)(rb + e) * NSLOT + bj] = rE[e];
                PP[(size_t)(rb + e) * NSLOT + bj] = rP[e];
            }
        }
    }

    if (!diag) {
#pragma unroll
        for (int n = 0; n < 4; ++n) {
            sec[n] += __shfl_xor(sec[n], 16, 64);
            sec[n] += __shfl_xor(sec[n], 32, 64);
            spc[n] += __shfl_xor(spc[n], 16, 64);
            spc[n] += __shfl_xor(spc[n], 32, 64);
        }
        if (quad == 0) {
#pragma unroll
            for (int n = 0; n < 4; ++n) {
                const int j = jBase + n * 16 + lrow;
                PE[(size_t)j * NSLOT + bi] = sec[n];
                PP[(size_t)j * NSLOT + bi] = spc[n];
            }
        }
    }
}

// 128 blocks x 64 rows. Per-block full label count (coalesced); thread
// (row = b*64 + t>>2, quarter q = t&3) sums PE/PP[row][32q..32q+32)
// (contiguous 128B); fold quarters by shuffle; loss; block-reduce; atomicAdd.
__global__ __launch_bounds__(256) void final_kernel(const float* __restrict__ PE,
                                                    const float* __restrict__ PP,
                                                    const int* __restrict__ lab,
                                                    float* __restrict__ out) {
    __shared__ float sh[4];
    __shared__ float shc;
    const int t = threadIdx.x;
    const int lane = t & 63, w = t >> 6;

    int cl = 0;
#pragma unroll 8
    for (int s = t; s < N_ROWS; s += 256) cl += lab[s];
#pragma unroll
    for (int off = 32; off >= 1; off >>= 1) cl += __shfl_xor(cl, off, 64);
    if (lane == 0) sh[w] = (float)cl;
    __syncthreads();
    if (t == 0) shc = sh[0] + sh[1] + sh[2] + sh[3];
    __syncthreads();
    const float c1 = shc;

    const int r = blockIdx.x * 64 + (t >> 2);
    const int q = t & 3;
    const float4* pe = (const float4*)(PE + (size_t)r * NSLOT + 32 * q);
    const float4* pp = (const float4*)(PP + (size_t)r * NSLOT + 32 * q);
    float se = 0.0f, sp = 0.0f;
#pragma unroll
    for (int v = 0; v < 8; ++v) {
        const float4 e4 = pe[v];
        const float4 p4 = pp[v];
        se += e4.x + e4.y + e4.z + e4.w;
        sp += p4.x + p4.y + p4.z + p4.w;
    }
#pragma unroll
    for (int off = 2; off >= 1; off >>= 1) {
        se += __shfl_xor(se, off, 64);
        sp += __shfl_xor(sp, off, 64);
    }

    float local = 0.0f;
    if (q == 0) {
        const int li = lab[r];
        const float np = (li ? c1 : (float)N_ROWS - c1) - 1.0f;
        local = (np * __logf(se) - sp) / (np + 1e-8f);
    }
#pragma unroll
    for (int off = 32; off >= 1; off >>= 1) local += __shfl_xor(local, off, 64);
    __syncthreads();
    if (lane == 0) sh[w] = local;
    __syncthreads();
    if (t == 0)
        atomicAdd(out, (sh[0] + sh[1] + sh[2] + sh[3]) * (1.0f / (float)N_ROWS));
}

extern "C" void kernel_launch(void* const* d_in, const int* in_sizes, int n_in,
                              void* d_out, int out_size, void* d_ws, size_t ws_size,
                              hipStream_t stream) {
    const float* features = (const float*)d_in[0];
    const int* labels = (const int*)d_in[1];
    float* out = (float*)d_out;

    char* ws = (char*)d_ws;
    uint8_t* f8 = (uint8_t*)ws;                              // 4 MiB
    float* PE = (float*)(ws + (size_t)N_ROWS * DIMB);        // 4 MiB [row][slot]
    float* PP = PE + (size_t)N_ROWS * NSLOT;                 // 4 MiB [row][slot]

    norm_kernel<<<N_ROWS / 4, 256, 0, stream>>>(features, f8, out);
    sim_kernel<<<NTRI, 64, 0, stream>>>(f8, labels, PE, PP);
    final_kernel<<<128, 256, 0, stream>>>(PE, PP, labels, out);
}

// Round 15
// 114.100 us; speedup vs baseline: 1.3408x; 1.3408x over previous
//
#include <hip/hip_runtime.h>
#include <hip/hip_bf16.h>
#include <stdint.h>

// ContrastiveLoss: N=8192, D=512 fp32 features, int labels {0,1}.
// out = mean_i [ (np_i * log(sum_exp_i) - sum_pos_i) / (np_i + 1e-8) ]
// R1: global_load_lds(16B) + XOR-swizzled LDS (bank-floor b128 reads).
// R2: upper-triangle tiles (2080). R5: fp8-e4m3 (x16 pre-scale; k
//     pre-permuted identically for A/B -> dot-invariant).
// R7: XCD swizzle. R9: pipelined dbuf K-loop. R13: PE/PP [row][slot].
// R14 post-mortem: register-direct GEMM (no LDS) regressed 87 us -- LDS
//     staging's value is converting 64 scattered-line loads into 2
//     wave-wide DMAs, not byte savings. Reverted.
// R15: R13 champion + merged (E,P) into one float2 array PEP[row][slot]:
//     halves epilogue store instructions + line touches; final reads
//     1KB/row contiguous.

#define N_ROWS 8192
#define DIMF 512
#define DIMB 512
#define NB 64
#define NSLOT 128
#define SIM_SCALE 0.0390625f  // 10 / 256  (features pre-scaled by 16)

typedef float f32x4 __attribute__((ext_vector_type(4)));
typedef int64_t i64x2 __attribute__((ext_vector_type(2)));

__device__ static inline void gload_lds16(const uint8_t* g, uint8_t* l) {
    __builtin_amdgcn_global_load_lds(
        (const __attribute__((address_space(1))) unsigned int*)g,
        (__attribute__((address_space(3))) unsigned int*)l, 16, 0, 0);
}

// 4 waves/block, one row per wave: fp32 sumsq -> scale by 16/norm -> fp8,
// k-permuted per 64B tile: orig (c,q) byte-group -> q*16 + c*8 (dot-invariant
// since A and B sides use the same permutation). Block 0 zeroes out[0].
__global__ __launch_bounds__(256) void norm_kernel(const float* __restrict__ x,
                                                   uint8_t* __restrict__ f8,
                                                   float* __restrict__ out) {
    const int wave = threadIdx.x >> 6, t = threadIdx.x & 63;
    const int row = blockIdx.x * 4 + wave;
    const float4* xr = (const float4*)(x + (size_t)row * DIMF);
    float4 v0 = xr[2 * t];
    float4 v1 = xr[2 * t + 1];
    float ss = v0.x * v0.x + v0.y * v0.y + v0.z * v0.z + v0.w * v0.w +
               v1.x * v1.x + v1.y * v1.y + v1.z * v1.z + v1.w * v1.w;
#pragma unroll
    for (int off = 32; off >= 1; off >>= 1) ss += __shfl_xor(ss, off, 64);
    float s = 16.0f / fmaxf(sqrtf(ss), 1e-12f);
    int lo = 0, hi = 0;
    lo = __builtin_amdgcn_cvt_pk_fp8_f32(v0.x * s, v0.y * s, lo, false);
    lo = __builtin_amdgcn_cvt_pk_fp8_f32(v0.z * s, v0.w * s, lo, true);
    hi = __builtin_amdgcn_cvt_pk_fp8_f32(v1.x * s, v1.y * s, hi, false);
    hi = __builtin_amdgcn_cvt_pk_fp8_f32(v1.z * s, v1.w * s, hi, true);
    int2 pk;
    pk.x = lo;
    pk.y = hi;
    const int pos = (t >> 3) * 64 + (t & 3) * 16 + ((t >> 2) & 1) * 8;
    *(int2*)(f8 + (size_t)row * DIMB + pos) = pk;
    if (blockIdx.x == 0 && threadIdx.x == 0) out[0] = 0.0f;
}

// 128x128 tile/block (4 waves 2x2, each 64x64 via 4x4x2 MFMA 16x16x32 fp8).
// BK=64B, double-buffered, pipelined: batch kk+1 issued after barrier kk,
// before compute kk -> barrier drains a compute-phase-old batch (free).
// PEP is [row][slot] float2 (E,P); slot = 2*bj+wn (rows), 2*bi+wm (cols).
__global__ __launch_bounds__(256, 4) void sim_kernel(const uint8_t* __restrict__ f8,
                                                     const int* __restrict__ lab,
                                                     float2* __restrict__ PEP) {
    __shared__ __align__(16) uint8_t sA[2][128 * 64];
    __shared__ __align__(16) uint8_t sB[2][128 * 64];

    // XCD-locality swizzle (2080 = 8 * 260); decode upper-triangle index.
    const int tblk = (blockIdx.x & 7) * 260 + (blockIdx.x >> 3);
    int bi = (int)(64.5f - sqrtf(64.5f * 64.5f - 2.0f * (float)tblk));
    while (bi * (129 - bi) / 2 > tblk) --bi;
    while ((bi + 1) * (128 - bi) / 2 <= tblk) ++bi;
    const int bj = bi + (tblk - bi * (129 - bi) / 2);
    const bool diag = (bi == bj);

    const int t = threadIdx.x;
    const int iBase = bi * 128, jBase = bj * 128;
    const int lane = t & 63, wave = t >> 6;
    const int wm = wave >> 1, wn = wave & 1;
    const int lrow = lane & 15, quad = lane >> 4;

    const int sub = lane >> 2;
    const int lu = (lane & 3) ^ ((sub >> 1) & 3);
    const size_t gA0 = (size_t)(iBase + wave * 32 + sub) * DIMB + lu * 16;
    const size_t gB0 = (size_t)(jBase + wave * 32 + sub) * DIMB + lu * 16;

    f32x4 acc[4][4] = {};

#pragma unroll
    for (int c = 0; c < 2; ++c) {
        gload_lds16(f8 + gA0 + (size_t)(c * 16) * DIMB, sA[0] + (wave * 32 + c * 16) * 64);
        gload_lds16(f8 + gB0 + (size_t)(c * 16) * DIMB, sB[0] + (wave * 32 + c * 16) * 64);
    }

#pragma unroll
    for (int kk = 0; kk < 8; ++kk) {
        const int cur = kk & 1;
        __syncthreads();
        if (kk < 7) {
#pragma unroll
            for (int c = 0; c < 2; ++c) {
                gload_lds16(f8 + gA0 + (size_t)(c * 16) * DIMB + (kk + 1) * 64,
                            sA[cur ^ 1] + (wave * 32 + c * 16) * 64);
                gload_lds16(f8 + gB0 + (size_t)(c * 16) * DIMB + (kk + 1) * 64,
                            sB[cur ^ 1] + (wave * 32 + c * 16) * 64);
            }
        }
        const int pu = (quad ^ ((lrow >> 1) & 3)) * 16;
        i64x2 af[4], bfr[4];
#pragma unroll
        for (int m = 0; m < 4; ++m)
            af[m] = *(const i64x2*)(sA[cur] + (wm * 64 + m * 16 + lrow) * 64 + pu);
#pragma unroll
        for (int n = 0; n < 4; ++n)
            bfr[n] = *(const i64x2*)(sB[cur] + (wn * 64 + n * 16 + lrow) * 64 + pu);
#pragma unroll
        for (int m = 0; m < 4; ++m)
#pragma unroll
            for (int n = 0; n < 4; ++n) {
                acc[m][n] = __builtin_amdgcn_mfma_f32_16x16x32_fp8_fp8(
                    af[m].x, bfr[n].x, acc[m][n], 0, 0, 0);
                acc[m][n] = __builtin_amdgcn_mfma_f32_16x16x32_fp8_fp8(
                    af[m].y, bfr[n].y, acc[m][n], 0, 0, 0);
            }
    }

    // Register-only epilogue. C/D layout: col=lane&15, row=quad*4+reg.
    int labj[4];
#pragma unroll
    for (int n = 0; n < 4; ++n) labj[n] = lab[jBase + wn * 64 + n * 16 + lrow];

    const int slotR = 2 * bj + wn;  // rows of iBase
    const int slotC = 2 * bi + wm;  // cols of jBase
    float sec[4] = {0, 0, 0, 0}, spc[4] = {0, 0, 0, 0};

#pragma unroll
    for (int m = 0; m < 4; ++m) {
        float rE[4], rP[4];
#pragma unroll
        for (int e = 0; e < 4; ++e) {
            const int r = wm * 64 + m * 16 + quad * 4 + e;
            const int i = iBase + r;
            const int labi = lab[i];
            float se = 0.0f, sp = 0.0f;
            if (diag) {
#pragma unroll
                for (int n = 0; n < 4; ++n) {
                    const int j = jBase + wn * 64 + n * 16 + lrow;
                    const float sim = acc[m][n][e] * SIM_SCALE;
                    if (j != i) {
                        se += __expf(sim);
                        if (labj[n] == labi) sp += sim;
                    }
                }
            } else {
#pragma unroll
                for (int n = 0; n < 4; ++n) {
                    const float sim = acc[m][n][e] * SIM_SCALE;
                    const float ex = __expf(sim);
                    se += ex;
                    sec[n] += ex;
                    if (labj[n] == labi) {
                        sp += sim;
                        spc[n] += sim;
                    }
                }
            }
#pragma unroll
            for (int off = 8; off >= 1; off >>= 1) {
                se += __shfl_xor(se, off, 16);
                sp += __shfl_xor(sp, off, 16);
            }
            rE[e] = se;
            rP[e] = sp;
        }
        if (lrow == 0) {
            const int rb = iBase + wm * 64 + m * 16 + quad * 4;
#pragma unroll
            for (int e = 0; e < 4; ++e) {
                float2 v;
                v.x = rE[e];
                v.y = rP[e];
                PEP[(size_t)(rb + e) * NSLOT + slotR] = v;
            }
        }
    }

    if (!diag) {
#pragma unroll
        for (int n = 0; n < 4; ++n) {
            sec[n] += __shfl_xor(sec[n], 16, 64);
            sec[n] += __shfl_xor(sec[n], 32, 64);
            spc[n] += __shfl_xor(spc[n], 16, 64);
            spc[n] += __shfl_xor(spc[n], 32, 64);
        }
        if (quad == 0) {
#pragma unroll
            for (int n = 0; n < 4; ++n) {
                const int j = jBase + wn * 64 + n * 16 + lrow;
                float2 v;
                v.x = sec[n];
                v.y = spc[n];
                PEP[(size_t)j * NSLOT + slotC] = v;
            }
        }
    }
}

// 128 blocks x 64 rows. Per-block full label count (coalesced); thread
// (row = b*64 + t>>2, quarter q = t&3) sums PEP[row][32q..32q+32) --
// 256B contiguous float2s; fold quarters by shuffle; loss; block-reduce.
__global__ __launch_bounds__(256) void final_kernel(const float2* __restrict__ PEP,
                                                    const int* __restrict__ lab,
                                                    float* __restrict__ out) {
    __shared__ float sh[4];
    __shared__ float shc;
    const int t = threadIdx.x;
    const int lane = t & 63, w = t >> 6;

    int cl = 0;
#pragma unroll 8
    for (int s = t; s < N_ROWS; s += 256) cl += lab[s];
#pragma unroll
    for (int off = 32; off >= 1; off >>= 1) cl += __shfl_xor(cl, off, 64);
    if (lane == 0) sh[w] = (float)cl;
    __syncthreads();
    if (t == 0) shc = sh[0] + sh[1] + sh[2] + sh[3];
    __syncthreads();
    const float c1 = shc;

    const int r = blockIdx.x * 64 + (t >> 2);
    const int q = t & 3;
    const float4* pv = (const float4*)(PEP + (size_t)r * NSLOT + 32 * q);
    float se = 0.0f, sp = 0.0f;
#pragma unroll
    for (int v = 0; v < 16; ++v) {
        const float4 x4 = pv[v];  // (E,P,E,P)
        se += x4.x + x4.z;
        sp += x4.y + x4.w;
    }
#pragma unroll
    for (int off = 2; off >= 1; off >>= 1) {
        se += __shfl_xor(se, off, 64);
        sp += __shfl_xor(sp, off, 64);
    }

    float local = 0.0f;
    if (q == 0) {
        const int li = lab[r];
        const float np = (li ? c1 : (float)N_ROWS - c1) - 1.0f;
        local = (np * __logf(se) - sp) / (np + 1e-8f);
    }
#pragma unroll
    for (int off = 32; off >= 1; off >>= 1) local += __shfl_xor(local, off, 64);
    __syncthreads();
    if (lane == 0) sh[w] = local;
    __syncthreads();
    if (t == 0)
        atomicAdd(out, (sh[0] + sh[1] + sh[2] + sh[3]) * (1.0f / (float)N_ROWS));
}

extern "C" void kernel_launch(void* const* d_in, const int* in_sizes, int n_in,
                              void* d_out, int out_size, void* d_ws, size_t ws_size,
                              hipStream_t stream) {
    const float* features = (const float*)d_in[0];
    const int* labels = (const int*)d_in[1];
    float* out = (float*)d_out;

    char* ws = (char*)d_ws;
    uint8_t* f8 = (uint8_t*)ws;                              // 4 MiB
    float2* PEP = (float2*)(ws + (size_t)N_ROWS * DIMB);     // 8 MiB [row][slot]

    norm_kernel<<<N_ROWS / 4, 256, 0, stream>>>(features, f8, out);
    sim_kernel<<<NB * (NB + 1) / 2, 256, 0, stream>>>(f8, labels, PEP);
    final_kernel<<<128, 256, 0, stream>>>(PEP, labels, out);
}

// Round 16
// 112.055 us; speedup vs baseline: 1.3653x; 1.0183x over previous
//
#include <hip/hip_runtime.h>
#include <hip/hip_bf16.h>
#include <stdint.h>

// ContrastiveLoss: N=8192, D=512 fp32 features, int labels {0,1}.
// out = mean_i [ (np_i * log(sum_exp_i) - sum_pos_i) / (np_i + 1e-8) ]
// R1: global_load_lds(16B) + XOR-swizzled LDS (bank-floor b128 reads).
// R2: upper-triangle tiles (2080). R5: fp8-e4m3 (x16 pre-scale; k
//     pre-permuted identically for A/B -> dot-invariant).
// R7: XCD swizzle. R9: pipelined dbuf K-loop (sim 46.4 us in [slot][row]).
// R15: merged float2 (E,P). 114.1 us champion.
// R16: have both ends of the R13 tradeoff: PEP back to [slot][row] so sim
//     epilogue stores are contiguous (32B row-chunks, 128B col-chunks,
//     R9-proven sim 46.4), AND final stays coalesced by mapping rr=lane,
//     slot-quarter=wave (each wave reads 512B contiguous per slot),
//     quarter-fold via 2KB LDS.

#define N_ROWS 8192
#define DIMF 512
#define DIMB 512
#define NB 64
#define NSLOT 128
#define SIM_SCALE 0.0390625f  // 10 / 256  (features pre-scaled by 16)

typedef float f32x4 __attribute__((ext_vector_type(4)));
typedef int64_t i64x2 __attribute__((ext_vector_type(2)));

__device__ static inline void gload_lds16(const uint8_t* g, uint8_t* l) {
    __builtin_amdgcn_global_load_lds(
        (const __attribute__((address_space(1))) unsigned int*)g,
        (__attribute__((address_space(3))) unsigned int*)l, 16, 0, 0);
}

// 4 waves/block, one row per wave: fp32 sumsq -> scale by 16/norm -> fp8,
// k-permuted per 64B tile: orig (c,q) byte-group -> q*16 + c*8 (dot-invariant
// since A and B sides use the same permutation). Block 0 zeroes out[0].
__global__ __launch_bounds__(256) void norm_kernel(const float* __restrict__ x,
                                                   uint8_t* __restrict__ f8,
                                                   float* __restrict__ out) {
    const int wave = threadIdx.x >> 6, t = threadIdx.x & 63;
    const int row = blockIdx.x * 4 + wave;
    const float4* xr = (const float4*)(x + (size_t)row * DIMF);
    float4 v0 = xr[2 * t];
    float4 v1 = xr[2 * t + 1];
    float ss = v0.x * v0.x + v0.y * v0.y + v0.z * v0.z + v0.w * v0.w +
               v1.x * v1.x + v1.y * v1.y + v1.z * v1.z + v1.w * v1.w;
#pragma unroll
    for (int off = 32; off >= 1; off >>= 1) ss += __shfl_xor(ss, off, 64);
    float s = 16.0f / fmaxf(sqrtf(ss), 1e-12f);
    int lo = 0, hi = 0;
    lo = __builtin_amdgcn_cvt_pk_fp8_f32(v0.x * s, v0.y * s, lo, false);
    lo = __builtin_amdgcn_cvt_pk_fp8_f32(v0.z * s, v0.w * s, lo, true);
    hi = __builtin_amdgcn_cvt_pk_fp8_f32(v1.x * s, v1.y * s, hi, false);
    hi = __builtin_amdgcn_cvt_pk_fp8_f32(v1.z * s, v1.w * s, hi, true);
    int2 pk;
    pk.x = lo;
    pk.y = hi;
    const int pos = (t >> 3) * 64 + (t & 3) * 16 + ((t >> 2) & 1) * 8;
    *(int2*)(f8 + (size_t)row * DIMB + pos) = pk;
    if (blockIdx.x == 0 && threadIdx.x == 0) out[0] = 0.0f;
}

// 128x128 tile/block (4 waves 2x2, each 64x64 via 4x4x2 MFMA 16x16x32 fp8).
// BK=64B, double-buffered, pipelined: batch kk+1 issued after barrier kk,
// before compute kk -> barrier drains a compute-phase-old batch (free).
// PEP is [slot][row] float2 (E,P); slot = 2*bj+wn (rows), 2*bi+wm (cols).
// Coverage (slot 2b+h, row region r): r<b col-writer (b,r) wm=h; r==b diag
// rows wn=h; r>b row-writer... (symmetric proof as R13) -- exactly once.
__global__ __launch_bounds__(256, 4) void sim_kernel(const uint8_t* __restrict__ f8,
                                                     const int* __restrict__ lab,
                                                     float2* __restrict__ PEP) {
    __shared__ __align__(16) uint8_t sA[2][128 * 64];
    __shared__ __align__(16) uint8_t sB[2][128 * 64];

    // XCD-locality swizzle (2080 = 8 * 260); decode upper-triangle index.
    const int tblk = (blockIdx.x & 7) * 260 + (blockIdx.x >> 3);
    int bi = (int)(64.5f - sqrtf(64.5f * 64.5f - 2.0f * (float)tblk));
    while (bi * (129 - bi) / 2 > tblk) --bi;
    while ((bi + 1) * (128 - bi) / 2 <= tblk) ++bi;
    const int bj = bi + (tblk - bi * (129 - bi) / 2);
    const bool diag = (bi == bj);

    const int t = threadIdx.x;
    const int iBase = bi * 128, jBase = bj * 128;
    const int lane = t & 63, wave = t >> 6;
    const int wm = wave >> 1, wn = wave & 1;
    const int lrow = lane & 15, quad = lane >> 4;

    const int sub = lane >> 2;
    const int lu = (lane & 3) ^ ((sub >> 1) & 3);
    const size_t gA0 = (size_t)(iBase + wave * 32 + sub) * DIMB + lu * 16;
    const size_t gB0 = (size_t)(jBase + wave * 32 + sub) * DIMB + lu * 16;

    f32x4 acc[4][4] = {};

#pragma unroll
    for (int c = 0; c < 2; ++c) {
        gload_lds16(f8 + gA0 + (size_t)(c * 16) * DIMB, sA[0] + (wave * 32 + c * 16) * 64);
        gload_lds16(f8 + gB0 + (size_t)(c * 16) * DIMB, sB[0] + (wave * 32 + c * 16) * 64);
    }

#pragma unroll
    for (int kk = 0; kk < 8; ++kk) {
        const int cur = kk & 1;
        __syncthreads();
        if (kk < 7) {
#pragma unroll
            for (int c = 0; c < 2; ++c) {
                gload_lds16(f8 + gA0 + (size_t)(c * 16) * DIMB + (kk + 1) * 64,
                            sA[cur ^ 1] + (wave * 32 + c * 16) * 64);
                gload_lds16(f8 + gB0 + (size_t)(c * 16) * DIMB + (kk + 1) * 64,
                            sB[cur ^ 1] + (wave * 32 + c * 16) * 64);
            }
        }
        const int pu = (quad ^ ((lrow >> 1) & 3)) * 16;
        i64x2 af[4], bfr[4];
#pragma unroll
        for (int m = 0; m < 4; ++m)
            af[m] = *(const i64x2*)(sA[cur] + (wm * 64 + m * 16 + lrow) * 64 + pu);
#pragma unroll
        for (int n = 0; n < 4; ++n)
            bfr[n] = *(const i64x2*)(sB[cur] + (wn * 64 + n * 16 + lrow) * 64 + pu);
#pragma unroll
        for (int m = 0; m < 4; ++m)
#pragma unroll
            for (int n = 0; n < 4; ++n) {
                acc[m][n] = __builtin_amdgcn_mfma_f32_16x16x32_fp8_fp8(
                    af[m].x, bfr[n].x, acc[m][n], 0, 0, 0);
                acc[m][n] = __builtin_amdgcn_mfma_f32_16x16x32_fp8_fp8(
                    af[m].y, bfr[n].y, acc[m][n], 0, 0, 0);
            }
    }

    // Register-only epilogue. C/D layout: col=lane&15, row=quad*4+reg.
    int labj[4];
#pragma unroll
    for (int n = 0; n < 4; ++n) labj[n] = lab[jBase + wn * 64 + n * 16 + lrow];

    const int slotR = 2 * bj + wn;  // rows of iBase
    const int slotC = 2 * bi + wm;  // cols of jBase
    float sec[4] = {0, 0, 0, 0}, spc[4] = {0, 0, 0, 0};

#pragma unroll
    for (int m = 0; m < 4; ++m) {
        float rE[4], rP[4];
#pragma unroll
        for (int e = 0; e < 4; ++e) {
            const int r = wm * 64 + m * 16 + quad * 4 + e;
            const int i = iBase + r;
            const int labi = lab[i];
            float se = 0.0f, sp = 0.0f;
            if (diag) {
#pragma unroll
                for (int n = 0; n < 4; ++n) {
                    const int j = jBase + wn * 64 + n * 16 + lrow;
                    const float sim = acc[m][n][e] * SIM_SCALE;
                    if (j != i) {
                        se += __expf(sim);
                        if (labj[n] == labi) sp += sim;
                    }
                }
            } else {
#pragma unroll
                for (int n = 0; n < 4; ++n) {
                    const float sim = acc[m][n][e] * SIM_SCALE;
                    const float ex = __expf(sim);
                    se += ex;
                    sec[n] += ex;
                    if (labj[n] == labi) {
                        sp += sim;
                        spc[n] += sim;
                    }
                }
            }
#pragma unroll
            for (int off = 8; off >= 1; off >>= 1) {
                se += __shfl_xor(se, off, 16);
                sp += __shfl_xor(sp, off, 16);
            }
            rE[e] = se;
            rP[e] = sp;
        }
        if (lrow == 0) {
            // 4 consecutive rows -> 32B contiguous (two float4 stores)
            float2* dst = &PEP[(size_t)slotR * N_ROWS + iBase + wm * 64 + m * 16 + quad * 4];
            float4 v0 = {rE[0], rP[0], rE[1], rP[1]};
            float4 v1 = {rE[2], rP[2], rE[3], rP[3]};
            *(float4*)dst = v0;
            *(float4*)(dst + 2) = v1;
        }
    }

    if (!diag) {
#pragma unroll
        for (int n = 0; n < 4; ++n) {
            sec[n] += __shfl_xor(sec[n], 16, 64);
            sec[n] += __shfl_xor(sec[n], 32, 64);
            spc[n] += __shfl_xor(spc[n], 16, 64);
            spc[n] += __shfl_xor(spc[n], 32, 64);
        }
        if (quad == 0) {
            // 16 lanes x consecutive j -> 128B contiguous per n
#pragma unroll
            for (int n = 0; n < 4; ++n) {
                const int j = jBase + wn * 64 + n * 16 + lrow;
                float2 v;
                v.x = sec[n];
                v.y = spc[n];
                PEP[(size_t)slotC * N_ROWS + j] = v;
            }
        }
    }
}

// 128 blocks x 64 rows, [slot][row] layout. Thread (rr = t&63, q = t>>6):
// sums slots 32q..32q+32 for row r0+rr -- each wave instr reads 64
// consecutive rows of one slot = 512B contiguous. Quarter-fold via LDS,
// wave 0 computes per-row loss, reduces, atomicAdds the mean.
__global__ __launch_bounds__(256) void final_kernel(const float2* __restrict__ PEP,
                                                    const int* __restrict__ lab,
                                                    float* __restrict__ out) {
    __shared__ float sE[256], sP[256], sh[4];
    __shared__ float shc;
    const int t = threadIdx.x;
    const int rr = t & 63, q = t >> 6;

    int cl = 0;
#pragma unroll 8
    for (int s = t; s < N_ROWS; s += 256) cl += lab[s];
#pragma unroll
    for (int off = 32; off >= 1; off >>= 1) cl += __shfl_xor(cl, off, 64);
    if (rr == 0) sh[q] = (float)cl;
    __syncthreads();
    if (t == 0) shc = sh[0] + sh[1] + sh[2] + sh[3];

    const int r0 = blockIdx.x * 64;
    float se = 0.0f, sp = 0.0f;
#pragma unroll 8
    for (int v = 0; v < 32; ++v) {
        const float2 x = PEP[(size_t)(q * 32 + v) * N_ROWS + r0 + rr];
        se += x.x;
        sp += x.y;
    }
    sE[t] = se;
    sP[t] = sp;
    __syncthreads();

    float local = 0.0f;
    if (q == 0) {
        se = sE[rr] + sE[64 + rr] + sE[128 + rr] + sE[192 + rr];
        sp = sP[rr] + sP[64 + rr] + sP[128 + rr] + sP[192 + rr];
        const float c1 = shc;
        const int li = lab[r0 + rr];
        const float np = (li ? c1 : (float)N_ROWS - c1) - 1.0f;
        local = (np * __logf(se) - sp) / (np + 1e-8f);
#pragma unroll
        for (int off = 32; off >= 1; off >>= 1) local += __shfl_xor(local, off, 64);
    }
    if (t == 0) atomicAdd(out, local * (1.0f / (float)N_ROWS));
}

extern "C" void kernel_launch(void* const* d_in, const int* in_sizes, int n_in,
                              void* d_out, int out_size, void* d_ws, size_t ws_size,
                              hipStream_t stream) {
    const float* features = (const float*)d_in[0];
    const int* labels = (const int*)d_in[1];
    float* out = (float*)d_out;

    char* ws = (char*)d_ws;
    uint8_t* f8 = (uint8_t*)ws;                              // 4 MiB
    float2* PEP = (float2*)(ws + (size_t)N_ROWS * DIMB);     // 8 MiB [slot][row]

    norm_kernel<<<N_ROWS / 4, 256, 0, stream>>>(features, f8, out);
    sim_kernel<<<NB * (NB + 1) / 2, 256, 0, stream>>>(f8, labels, PEP);
    final_kernel<<<128, 256, 0, stream>>>(PEP, labels, out);
}